// Round 5
// baseline (290.801 us; speedup 1.0000x reference)
//
#include <hip/hip_runtime.h>
#include <math.h>

typedef __attribute__((ext_vector_type(8))) short bh8;    // 8 bf16 in 4 VGPRs
typedef __attribute__((ext_vector_type(4))) float f32x4;  // MFMA accumulator

namespace {
constexpr int Bn = 4, Tn = 2048, Cn = 1024, Hn = 16, Dn = 64, INNERn = 1024, OUTn = 1024;
constexpr int Mn = Bn * Tn;  // 8192 tokens
}

// async 16B global->LDS (wave-uniform base + lane*16 placement)
__device__ __forceinline__ void glds16(const void* g, void* l) {
    __builtin_amdgcn_global_load_lds(
        (const __attribute__((address_space(1))) void*)g,
        (__attribute__((address_space(3))) void*)l, 16, 0, 0);
}

// waitcnt vmcnt(0) lgkmcnt(0) + barrier — prefetch-friendly (loads issued at
// iter top are a full body old by the time we wait).
__device__ __forceinline__ void barrier_vm0() {
    __builtin_amdgcn_s_waitcnt(0x0070);
    __builtin_amdgcn_s_barrier();
}

// fp32 -> bf16 round-to-nearest-even
__device__ __forceinline__ ushort f2bf(float f) {
    union { float f; unsigned u; } v; v.f = f;
    unsigned r = v.u + 0x7fffu + ((v.u >> 16) & 1u);
    return (ushort)(r >> 16);
}
__device__ __forceinline__ unsigned pack_rne(float a, float b) {
    return (unsigned)f2bf(a) | ((unsigned)f2bf(b) << 16);
}
// truncation-pack: low16 = trunc(a), high16 = trunc(b)  (1 VALU op)
__device__ __forceinline__ unsigned pack_trunc(float a, float b) {
    return __builtin_amdgcn_perm(__float_as_uint(a), __float_as_uint(b), 0x03020706u);
}

// one launch: x (8192 blocks) + 4 weights (1024 blocks each)
__global__ __launch_bounds__(256)
void cvt_all(const float* __restrict__ x,  const float* __restrict__ Wk,
             const float* __restrict__ Wq, const float* __restrict__ Wv,
             const float* __restrict__ Wp,
             ushort* __restrict__ xb,  ushort* __restrict__ wkb,
             ushort* __restrict__ wqb, ushort* __restrict__ wvb,
             ushort* __restrict__ wpb)
{
    const int bid = blockIdx.x;
    const float* s; ushort* d; float sc; int i;
    if (bid < 8192) {
        s = x; d = xb; sc = 0.03125f;             // fold C^-0.5 (exact pow2)
        i = bid * 256 + threadIdx.x;
    } else {
        const int seg = (bid - 8192) >> 10;
        i = ((bid - 8192) & 1023) * 256 + threadIdx.x;
        s  = (seg == 0) ? Wk : (seg == 1) ? Wq : (seg == 2) ? Wv : Wp;
        d  = (seg == 0) ? wkb : (seg == 1) ? wqb : (seg == 2) ? wvb : wpb;
        sc = (seg == 3) ? 0.03125f : 1.0f;        // fold INNER^-0.5 into Wp
    }
    float4 f = ((const float4*)s)[i];
    ushort4 o;
    o.x = f2bf(f.x * sc); o.y = f2bf(f.y * sc);
    o.z = f2bf(f.z * sc); o.w = f2bf(f.w * sc);
    ((ushort4*)d)[i] = o;
}

// ---------------------------------------------------------------------------
// Fused QKV projection GEMM (128x128 tile, BK=32, dbuf, single vm0-barrier
// per K-iter). Q/K out: bf16 [B,H,T,D]; V out: bf16 [B,H,D,T] (transposed).
// ---------------------------------------------------------------------------
__global__ __launch_bounds__(256)
void gemm_qkv(const ushort* __restrict__ A, const ushort* __restrict__ Wq,
              const ushort* __restrict__ Wk, const ushort* __restrict__ Wv,
              ushort* __restrict__ Oq, ushort* __restrict__ Ok,
              ushort* __restrict__ Ovt, float qscale)
{
    __shared__ char As[2][8192];   // addr(m,k) = m*64 + k*2
    __shared__ char Bs[2][8192];
    const int tid = threadIdx.x;
    const int w = tid >> 6, lane = tid & 63, quad = lane >> 4, l = lane & 15;
    const int sel = blockIdx.x >> 3;
    const ushort* Bw = (sel == 0) ? Wq : (sel == 1) ? Wk : Wv;
    const int n0 = (blockIdx.x & 7) * 128, m0 = blockIdx.y * 128;
    const int wm = w >> 1, wn = w & 1;

    auto stage = [&](int bsel, int k0) {
#pragma unroll
        for (int rr = 0; rr < 2; ++rr) {
            const int rho = w * 2 + rr;
            const int row = rho * 16 + (lane >> 2);
            const int kq  = (lane & 3) * 8;
            glds16(A  + (size_t)(m0 + row) * Cn + k0 + kq, As[bsel] + rho * 1024 + lane * 16);
            glds16(Bw + (size_t)(n0 + row) * Cn + k0 + kq, Bs[bsel] + rho * 1024 + lane * 16);
        }
    };

    f32x4 acc[4][4];
#pragma unroll
    for (int i = 0; i < 4; ++i)
#pragma unroll
        for (int j = 0; j < 4; ++j) acc[i][j] = (f32x4){0.f, 0.f, 0.f, 0.f};

    stage(0, 0);
    barrier_vm0();
#pragma unroll 2
    for (int it = 0; it < 32; ++it) {
        const int cur = it & 1;
        if (it < 31) stage(cur ^ 1, (it + 1) * 32);
        const char* Ac = As[cur]; const char* Bc = Bs[cur];
        bh8 af[4], bf[4];
#pragma unroll
        for (int mf = 0; mf < 4; ++mf)
            af[mf] = *(const bh8*)(Ac + (wm * 64 + mf * 16 + l) * 64 + quad * 16);
#pragma unroll
        for (int nf = 0; nf < 4; ++nf)
            bf[nf] = *(const bh8*)(Bc + (wn * 64 + nf * 16 + l) * 64 + quad * 16);
#pragma unroll
        for (int mf = 0; mf < 4; ++mf)
#pragma unroll
            for (int nf = 0; nf < 4; ++nf)
                acc[mf][nf] = __builtin_amdgcn_mfma_f32_16x16x32_bf16(af[mf], bf[nf], acc[mf][nf], 0, 0, 0);
        barrier_vm0();
    }

    // epilogue: C/D layout col = l, row = quad*4 + reg
    if (sel < 2) {
        ushort* dU = (sel == 0) ? Oq : Ok;
        const float scale = (sel == 0) ? qscale : 1.0f;
#pragma unroll
        for (int mf = 0; mf < 4; ++mf)
#pragma unroll
            for (int nf = 0; nf < 4; ++nf) {
                const int mb = m0 + wm * 64 + mf * 16 + quad * 4;
                const int n  = n0 + wn * 64 + nf * 16 + l;
                const int h = n >> 6, dd = n & 63;
#pragma unroll
                for (int reg = 0; reg < 4; ++reg) {
                    const int m = mb + reg;
                    const int b = m >> 11, t = m & (Tn - 1);
                    dU[((size_t)(b * Hn + h) * Tn + t) * Dn + dd] = f2bf(acc[mf][nf][reg] * scale);
                }
            }
    } else {
#pragma unroll
        for (int mf = 0; mf < 4; ++mf)
#pragma unroll
            for (int nf = 0; nf < 4; ++nf) {
                const int mb = m0 + wm * 64 + mf * 16 + quad * 4;
                const int n  = n0 + wn * 64 + nf * 16 + l;
                const int h = n >> 6, dd = n & 63;
                const int b = mb >> 11, t0 = mb & (Tn - 1);
                uint2 p;
                p.x = pack_rne(acc[mf][nf][0], acc[mf][nf][1]);
                p.y = pack_rne(acc[mf][nf][2], acc[mf][nf][3]);
                *(uint2*)(Ovt + ((size_t)(b * Hn + h) * Dn + dd) * Tn + t0) = p;
            }
    }
}

// ---------------------------------------------------------------------------
// Output projection: out = ao(8192x1024) * Wp(1024x1024)^T, fp32 out.
// ---------------------------------------------------------------------------
__global__ __launch_bounds__(256)
void gemm_po(const ushort* __restrict__ A, const ushort* __restrict__ Bw,
             float* __restrict__ Cout)
{
    __shared__ char As[2][8192];
    __shared__ char Bs[2][8192];
    const int tid = threadIdx.x;
    const int w = tid >> 6, lane = tid & 63, quad = lane >> 4, l = lane & 15;
    const int n0 = blockIdx.x * 128, m0 = blockIdx.y * 128;
    const int wm = w >> 1, wn = w & 1;

    auto stage = [&](int bsel, int k0) {
#pragma unroll
        for (int rr = 0; rr < 2; ++rr) {
            const int rho = w * 2 + rr;
            const int row = rho * 16 + (lane >> 2);
            const int kq  = (lane & 3) * 8;
            glds16(A  + (size_t)(m0 + row) * Cn + k0 + kq, As[bsel] + rho * 1024 + lane * 16);
            glds16(Bw + (size_t)(n0 + row) * Cn + k0 + kq, Bs[bsel] + rho * 1024 + lane * 16);
        }
    };

    f32x4 acc[4][4];
#pragma unroll
    for (int i = 0; i < 4; ++i)
#pragma unroll
        for (int j = 0; j < 4; ++j) acc[i][j] = (f32x4){0.f, 0.f, 0.f, 0.f};

    stage(0, 0);
    barrier_vm0();
#pragma unroll 2
    for (int it = 0; it < 32; ++it) {
        const int cur = it & 1;
        if (it < 31) stage(cur ^ 1, (it + 1) * 32);
        const char* Ac = As[cur]; const char* Bc = Bs[cur];
        bh8 af[4], bf[4];
#pragma unroll
        for (int mf = 0; mf < 4; ++mf)
            af[mf] = *(const bh8*)(Ac + (wm * 64 + mf * 16 + l) * 64 + quad * 16);
#pragma unroll
        for (int nf = 0; nf < 4; ++nf)
            bf[nf] = *(const bh8*)(Bc + (wn * 64 + nf * 16 + l) * 64 + quad * 16);
#pragma unroll
        for (int mf = 0; mf < 4; ++mf)
#pragma unroll
            for (int nf = 0; nf < 4; ++nf)
                acc[mf][nf] = __builtin_amdgcn_mfma_f32_16x16x32_bf16(af[mf], bf[nf], acc[mf][nf], 0, 0, 0);
        barrier_vm0();
    }

#pragma unroll
    for (int mf = 0; mf < 4; ++mf)
#pragma unroll
        for (int nf = 0; nf < 4; ++nf) {
            const int mb = m0 + wm * 64 + mf * 16 + quad * 4;
            const int n  = n0 + wn * 64 + nf * 16 + l;
#pragma unroll
            for (int reg = 0; reg < 4; ++reg)
                Cout[(size_t)(mb + reg) * OUTn + n] = acc[mf][nf][reg];
        }
}

// ---------------------------------------------------------------------------
// MFMA flash attention v3. S^T formulation, streaming softmax (no running
// max — scores bounded; exp2 domain, log2e folded into q). l via ones-MFMA
// over the same truncated bf16 P used for PV.
// Block = (b,h, 256 q), 4 waves x 64 q (4 n-tiles) — K/V LDS frag reads
// amortize over 2x more work than v2. 64-key iters, K/V double-buffered,
// single vm0-barrier per iter. PV runs in two 32-key halves so the per-wave
// P buffer stays 4KB (LDS total 48KB, grid 512 = exactly 2 blocks/CU).
// ---------------------------------------------------------------------------
__global__ __launch_bounds__(256, 2)
void attn_mfma(const ushort* __restrict__ Qg, const ushort* __restrict__ Kg,
               const ushort* __restrict__ Vtg, ushort* __restrict__ Og)
{
    __shared__ char KT[2][8192];  // (r,d): (d>>5)*4096 + r*64 + (d&31)*2
    __shared__ char VT[2][8192];  // (c,d): d*128 + ((c>>3)^(d&7))*16 + (c&7)*2
    __shared__ char PS[16384];    // per-wave 4KB: (q,kk): q*64 + chunk-XOR(l&3)

    const int tid = threadIdx.x;
    const int w = tid >> 6, lane = tid & 63, quad = lane >> 4, l = lane & 15;
    const int q0 = blockIdx.x * 256;
    const int bh = blockIdx.y, b = bh >> 4, h = bh & 15;
    const ushort* Qp = Qg  + (size_t)bh * Tn * Dn;
    const ushort* Kp = Kg  + (size_t)bh * Tn * Dn;
    const ushort* Vp = Vtg + (size_t)bh * Dn * Tn;   // [d][t]

    auto stageK = [&](char* buf, int kt) {
#pragma unroll
        for (int rr = 0; rr < 2; ++rr) {
            const int rho = w * 2 + rr;                    // 0..7
            const int r  = (rho & 3) * 16 + (lane >> 2);   // key row 0..63
            const int dq = (rho >> 2) * 32 + (lane & 3) * 8;
            glds16(Kp + (size_t)(kt * 64 + r) * Dn + dq, buf + rho * 1024 + lane * 16);
        }
    };
    auto stageV = [&](char* buf, int kt) {
#pragma unroll
        for (int rr = 0; rr < 2; ++rr) {
            const int rho = w * 2 + rr;
            const int d = rho * 8 + (lane >> 3);           // 0..63
            const int csrc = (lane & 7) ^ ((lane >> 3) & 7);
            glds16(Vp + (size_t)d * Tn + kt * 64 + csrc * 8, buf + rho * 1024 + lane * 16);
        }
    };

    // ---- Q frags direct from global (B-operand layout; once per block) ----
    bh8 qf[4][2];
#pragma unroll
    for (int nt = 0; nt < 4; ++nt)
#pragma unroll
        for (int ks = 0; ks < 2; ++ks)
            qf[nt][ks] = *(const bh8*)(Qp + (size_t)(q0 + w * 64 + nt * 16 + l) * Dn + ks * 32 + quad * 8);

    bh8 ones;
#pragma unroll
    for (int i = 0; i < 8; ++i) ones[i] = (short)0x3F80;   // bf16 1.0

    f32x4 oacc[4][4], lacc[4];
#pragma unroll
    for (int nt = 0; nt < 4; ++nt) {
        lacc[nt] = (f32x4){0.f, 0.f, 0.f, 0.f};
#pragma unroll
        for (int dt = 0; dt < 4; ++dt) oacc[nt][dt] = (f32x4){0.f, 0.f, 0.f, 0.f};
    }

    char* Pw = PS + w * 4096;
    const f32x4 zero = (f32x4){0.f, 0.f, 0.f, 0.f};

    stageK(KT[0], 0);
    stageV(VT[0], 0);
    barrier_vm0();

    for (int kt = 0; kt < Tn / 64; ++kt) {
        const int cur = kt & 1;
        if (kt < Tn / 64 - 1) {           // prefetch next tile (in flight all body)
            stageK(KT[cur ^ 1], kt + 1);
            stageV(VT[cur ^ 1], kt + 1);
        }
        const char* Kc = KT[cur];
        const char* Vc = VT[cur];

        // ---- two 32-key halves: S -> exp -> P-stash -> PV ----
#pragma unroll
        for (int hh = 0; hh < 2; ++hh) {
            // K frags for keys hh*32..+31 (A-operand: m=key, k=d)
            bh8 kf[2][2];
#pragma unroll
            for (int k8l = 0; k8l < 2; ++k8l)
#pragma unroll
                for (int ks = 0; ks < 2; ++ks)
                    kf[k8l][ks] = *(const bh8*)(Kc + ks * 4096 + ((hh * 2 + k8l) * 16 + l) * 64 + quad * 16);

            // S^T = K Q^T : rows=keys(quad*4+reg), col=q(l)
            f32x4 st[4][2];
#pragma unroll
            for (int nt = 0; nt < 4; ++nt)
#pragma unroll
                for (int k8l = 0; k8l < 2; ++k8l) {
                    st[nt][k8l] = __builtin_amdgcn_mfma_f32_16x16x32_bf16(kf[k8l][0], qf[nt][0], zero, 0, 0, 0);
                    st[nt][k8l] = __builtin_amdgcn_mfma_f32_16x16x32_bf16(kf[k8l][1], qf[nt][1], st[nt][k8l], 0, 0, 0);
                }

            // P = exp2(S) -> trunc-bf16 -> wave-private PS
            // (DS ops complete in order: the kf reads above already forced
            //  the lgkm drain of last half's PS reads before these writes)
#pragma unroll
            for (int nt = 0; nt < 4; ++nt)
#pragma unroll
                for (int k8l = 0; k8l < 2; ++k8l) {
                    const float e0 = __builtin_amdgcn_exp2f(st[nt][k8l][0]);
                    const float e1 = __builtin_amdgcn_exp2f(st[nt][k8l][1]);
                    const float e2 = __builtin_amdgcn_exp2f(st[nt][k8l][2]);
                    const float e3 = __builtin_amdgcn_exp2f(st[nt][k8l][3]);
                    uint2 p;
                    p.x = pack_trunc(e0, e1);
                    p.y = pack_trunc(e2, e3);
                    const int x = (k8l * 2 + (quad >> 1)) ^ (l & 3);
                    *(uint2*)(Pw + (nt * 16 + l) * 64 + x * 16 + (quad & 1) * 8) = p;
                }
            __builtin_amdgcn_s_waitcnt(0xC07F);  // lgkmcnt(0): PS visible to own wave

            // O += P V ; l += ones*P (B-operand pf: n=q, k=keys of half)
            bh8 pf[4];
#pragma unroll
            for (int nt = 0; nt < 4; ++nt)
                pf[nt] = *(const bh8*)(Pw + (nt * 16 + l) * 64 + ((quad ^ (l & 3)) * 16));
#pragma unroll
            for (int nt = 0; nt < 4; ++nt)
                lacc[nt] = __builtin_amdgcn_mfma_f32_16x16x32_bf16(ones, pf[nt], lacc[nt], 0, 0, 0);
#pragma unroll
            for (int dt = 0; dt < 4; ++dt) {
                bh8 vf = *(const bh8*)(Vc + (dt * 16 + l) * 128 + (((hh * 4 + quad) ^ (l & 7)) * 16));
#pragma unroll
                for (int nt = 0; nt < 4; ++nt)
                    oacc[nt][dt] = __builtin_amdgcn_mfma_f32_16x16x32_bf16(vf, pf[nt], oacc[nt][dt], 0, 0, 0);
            }
        }
        barrier_vm0();   // prefetch drained; all waves done with KT/VT cur
    }

    // ---- epilogue: normalize, write bf16 [B,T,H*D]; O^T: col=q(l), row=d ----
#pragma unroll
    for (int nt = 0; nt < 4; ++nt) {
        const float inv = 1.0f / lacc[nt][0];
        const int t = q0 + w * 64 + nt * 16 + l;
#pragma unroll
        for (int dt = 0; dt < 4; ++dt) {
            uint2 p;
            p.x = pack_rne(oacc[nt][dt][0] * inv, oacc[nt][dt][1] * inv);
            p.y = pack_rne(oacc[nt][dt][2] * inv, oacc[nt][dt][3] * inv);
            *(uint2*)(Og + ((size_t)(b * Tn + t)) * INNERn + h * 64 + dt * 16 + quad * 4) = p;
        }
    }
}

// ---------------------------------------------------------------------------
extern "C" void kernel_launch(void* const* d_in, const int* in_sizes, int n_in,
                              void* d_out, int out_size, void* d_ws, size_t ws_size,
                              hipStream_t stream)
{
    const float* x  = (const float*)d_in[0];
    const float* Wk = (const float*)d_in[1];
    const float* Wq = (const float*)d_in[2];
    const float* Wv = (const float*)d_in[3];
    const float* Wp = (const float*)d_in[4];
    float* out = (float*)d_out;

    // workspace (all bf16): x | Wk | Wq | Wv | Wp | q | k | vT | ao
    ushort* xb  = (ushort*)d_ws;
    ushort* wkb = xb  + (size_t)Mn * Cn;
    ushort* wqb = wkb + (size_t)INNERn * Cn;
    ushort* wvb = wqb + (size_t)INNERn * Cn;
    ushort* wpb = wvb + (size_t)INNERn * Cn;
    ushort* qw  = wpb + (size_t)OUTn * INNERn;
    ushort* kw  = qw  + (size_t)Mn * INNERn;
    ushort* vtw = kw  + (size_t)Mn * INNERn;   // [B,H,D,T]
    ushort* aow = vtw + (size_t)Mn * INNERn;

    const dim3 blk(256);
    cvt_all<<<dim3(8192 + 4096), blk, 0, stream>>>(x, Wk, Wq, Wv, Wp,
                                                   xb, wkb, wqb, wvb, wpb);

    // q folds d^-0.5 * log2(e) so softmax runs in exp2 domain
    gemm_qkv<<<dim3(3 * 8, Mn / 128), blk, 0, stream>>>(xb, wqb, wkb, wvb,
                                                        qw, kw, vtw, 0.125f * 1.44269504f);

    attn_mfma<<<dim3(Tn / 256, Bn * Hn), blk, 0, stream>>>(qw, kw, vtw, aow);

    gemm_po<<<dim3(OUTn / 128, Mn / 128), blk, 0, stream>>>(aow, wpb, out);
}

// Round 6
// 283.440 us; speedup vs baseline: 1.0260x; 1.0260x over previous
//
#include <hip/hip_runtime.h>
#include <math.h>

typedef __attribute__((ext_vector_type(8))) short bh8;    // 8 bf16 in 4 VGPRs
typedef __attribute__((ext_vector_type(4))) float f32x4;  // MFMA accumulator

namespace {
constexpr int Bn = 4, Tn = 2048, Cn = 1024, Hn = 16, Dn = 64, INNERn = 1024, OUTn = 1024;
constexpr int Mn = Bn * Tn;  // 8192 tokens
}

// async 16B global->LDS (wave-uniform base + lane*16 placement)
__device__ __forceinline__ void glds16(const void* g, void* l) {
    __builtin_amdgcn_global_load_lds(
        (const __attribute__((address_space(1))) void*)g,
        (__attribute__((address_space(3))) void*)l, 16, 0, 0);
}

// waitcnt vmcnt(0) lgkmcnt(0) + barrier — prefetch-friendly (loads issued at
// iter top are a full body old by the time we wait).
__device__ __forceinline__ void barrier_vm0() {
    __builtin_amdgcn_s_waitcnt(0x0070);
    __builtin_amdgcn_s_barrier();
}

// fp32 -> bf16 round-to-nearest-even
__device__ __forceinline__ ushort f2bf(float f) {
    union { float f; unsigned u; } v; v.f = f;
    unsigned r = v.u + 0x7fffu + ((v.u >> 16) & 1u);
    return (ushort)(r >> 16);
}
__device__ __forceinline__ unsigned pack_rne(float a, float b) {
    return (unsigned)f2bf(a) | ((unsigned)f2bf(b) << 16);
}
// truncation-pack: low16 = trunc(a), high16 = trunc(b)  (1 VALU op)
__device__ __forceinline__ unsigned pack_trunc(float a, float b) {
    return __builtin_amdgcn_perm(__float_as_uint(a), __float_as_uint(b), 0x03020706u);
}

// one launch: x (8192 blocks) + 4 weights (1024 blocks each)
__global__ __launch_bounds__(256)
void cvt_all(const float* __restrict__ x,  const float* __restrict__ Wk,
             const float* __restrict__ Wq, const float* __restrict__ Wv,
             const float* __restrict__ Wp,
             ushort* __restrict__ xb,  ushort* __restrict__ wkb,
             ushort* __restrict__ wqb, ushort* __restrict__ wvb,
             ushort* __restrict__ wpb)
{
    const int bid = blockIdx.x;
    const float* s; ushort* d; float sc; int i;
    if (bid < 8192) {
        s = x; d = xb; sc = 0.03125f;             // fold C^-0.5 (exact pow2)
        i = bid * 256 + threadIdx.x;
    } else {
        const int seg = (bid - 8192) >> 10;
        i = ((bid - 8192) & 1023) * 256 + threadIdx.x;
        s  = (seg == 0) ? Wk : (seg == 1) ? Wq : (seg == 2) ? Wv : Wp;
        d  = (seg == 0) ? wkb : (seg == 1) ? wqb : (seg == 2) ? wvb : wpb;
        sc = (seg == 3) ? 0.03125f : 1.0f;        // fold INNER^-0.5 into Wp
    }
    float4 f = ((const float4*)s)[i];
    ushort4 o;
    o.x = f2bf(f.x * sc); o.y = f2bf(f.y * sc);
    o.z = f2bf(f.z * sc); o.w = f2bf(f.w * sc);
    ((ushort4*)d)[i] = o;
}

// ---------------------------------------------------------------------------
// Fused QKV projection GEMM (128x128 tile, BK=32, dbuf, single vm0-barrier
// per K-iter). Q/K out: bf16 [B,H,T,D]; V out: bf16 [B,H,D,T] via LDS-staged
// coalesced stores (256B runs) instead of 4KB-strided uint2 scatter.
// ---------------------------------------------------------------------------
__global__ __launch_bounds__(256)
void gemm_qkv(const ushort* __restrict__ A, const ushort* __restrict__ Wq,
              const ushort* __restrict__ Wk, const ushort* __restrict__ Wv,
              ushort* __restrict__ Oq, ushort* __restrict__ Ok,
              ushort* __restrict__ Ovt, float qscale)
{
    __shared__ char SM[32768];     // As[2] | Bs[2]; reused for V^T epilogue
    char* As0 = SM;          char* As1 = SM + 8192;
    char* Bs0 = SM + 16384;  char* Bs1 = SM + 24576;
    const int tid = threadIdx.x;
    const int w = tid >> 6, lane = tid & 63, quad = lane >> 4, l = lane & 15;
    const int sel = blockIdx.x >> 3;
    const ushort* Bw = (sel == 0) ? Wq : (sel == 1) ? Wk : Wv;
    const int n0 = (blockIdx.x & 7) * 128, m0 = blockIdx.y * 128;
    const int wm = w >> 1, wn = w & 1;

    auto stage = [&](char* Ad, char* Bd, int k0) {
#pragma unroll
        for (int rr = 0; rr < 2; ++rr) {
            const int rho = w * 2 + rr;
            const int row = rho * 16 + (lane >> 2);
            const int kq  = (lane & 3) * 8;
            glds16(A  + (size_t)(m0 + row) * Cn + k0 + kq, Ad + rho * 1024 + lane * 16);
            glds16(Bw + (size_t)(n0 + row) * Cn + k0 + kq, Bd + rho * 1024 + lane * 16);
        }
    };

    f32x4 acc[4][4];
#pragma unroll
    for (int i = 0; i < 4; ++i)
#pragma unroll
        for (int j = 0; j < 4; ++j) acc[i][j] = (f32x4){0.f, 0.f, 0.f, 0.f};

    stage(As0, Bs0, 0);
    barrier_vm0();
#pragma unroll 2
    for (int it = 0; it < 32; ++it) {
        const int cur = it & 1;
        if (it < 31) stage(cur ? As0 : As1, cur ? Bs0 : Bs1, (it + 1) * 32);
        const char* Ac = cur ? As1 : As0; const char* Bc = cur ? Bs1 : Bs0;
        bh8 af[4], bf[4];
#pragma unroll
        for (int mf = 0; mf < 4; ++mf)
            af[mf] = *(const bh8*)(Ac + (wm * 64 + mf * 16 + l) * 64 + quad * 16);
#pragma unroll
        for (int nf = 0; nf < 4; ++nf)
            bf[nf] = *(const bh8*)(Bc + (wn * 64 + nf * 16 + l) * 64 + quad * 16);
#pragma unroll
        for (int mf = 0; mf < 4; ++mf)
#pragma unroll
            for (int nf = 0; nf < 4; ++nf)
                acc[mf][nf] = __builtin_amdgcn_mfma_f32_16x16x32_bf16(af[mf], bf[nf], acc[mf][nf], 0, 0, 0);
        barrier_vm0();
    }

    // epilogue: C/D layout col = l, row = quad*4 + reg
    if (sel < 2) {
        ushort* dU = (sel == 0) ? Oq : Ok;
        const float scale = (sel == 0) ? qscale : 1.0f;
#pragma unroll
        for (int mf = 0; mf < 4; ++mf)
#pragma unroll
            for (int nf = 0; nf < 4; ++nf) {
                const int mb = m0 + wm * 64 + mf * 16 + quad * 4;
                const int n  = n0 + wn * 64 + nf * 16 + l;
                const int h = n >> 6, dd = n & 63;
#pragma unroll
                for (int reg = 0; reg < 4; ++reg) {
                    const int m = mb + reg;
                    const int b = m >> 11, t = m & (Tn - 1);
                    dU[((size_t)(b * Hn + h) * Tn + t) * Dn + dd] = f2bf(acc[mf][nf][reg] * scale);
                }
            }
    } else {
        // V^T: stash tile [n][m] bf16 in LDS (XOR-swizzled 16B chunks), then
        // coalesced 256B-run stores into [B,H,D,T].
#pragma unroll
        for (int mf = 0; mf < 4; ++mf)
#pragma unroll
            for (int nf = 0; nf < 4; ++nf) {
                const int mb = wm * 64 + mf * 16 + quad * 4;   // tile-local m
                const int n  = wn * 64 + nf * 16 + l;          // tile-local n
                uint2 p;
                p.x = pack_rne(acc[mf][nf][0], acc[mf][nf][1]);
                p.y = pack_rne(acc[mf][nf][2], acc[mf][nf][3]);
                const int c = mb >> 3;                         // 16B chunk of m
                *(uint2*)(SM + n * 256 + ((c ^ (n & 15)) & 15) * 16 + (mb & 7) * 2) = p;
            }
        __syncthreads();
        const int bb = m0 >> 11, t0 = m0 & (Tn - 1);
#pragma unroll
        for (int it2 = 0; it2 < 8; ++it2) {
            const int n = it2 * 16 + w * 4 + quad;             // tile-local n
            const int ng = n0 + n;
            const int h = ng >> 6, dd = ng & 63;
            int4 vsm = *(const int4*)(SM + n * 256 + ((l ^ (n & 15)) & 15) * 16);
            *(int4*)(Ovt + ((size_t)(bb * Hn + h) * Dn + dd) * Tn + t0 + l * 8) = vsm;
        }
    }
}

// ---------------------------------------------------------------------------
// Output projection: out = ao(8192x1024) * Wp(1024x1024)^T, fp32 out.
// ---------------------------------------------------------------------------
__global__ __launch_bounds__(256)
void gemm_po(const ushort* __restrict__ A, const ushort* __restrict__ Bw,
             float* __restrict__ Cout)
{
    __shared__ char As[2][8192];
    __shared__ char Bs[2][8192];
    const int tid = threadIdx.x;
    const int w = tid >> 6, lane = tid & 63, quad = lane >> 4, l = lane & 15;
    const int n0 = blockIdx.x * 128, m0 = blockIdx.y * 128;
    const int wm = w >> 1, wn = w & 1;

    auto stage = [&](int bsel, int k0) {
#pragma unroll
        for (int rr = 0; rr < 2; ++rr) {
            const int rho = w * 2 + rr;
            const int row = rho * 16 + (lane >> 2);
            const int kq  = (lane & 3) * 8;
            glds16(A  + (size_t)(m0 + row) * Cn + k0 + kq, As[bsel] + rho * 1024 + lane * 16);
            glds16(Bw + (size_t)(n0 + row) * Cn + k0 + kq, Bs[bsel] + rho * 1024 + lane * 16);
        }
    };

    f32x4 acc[4][4];
#pragma unroll
    for (int i = 0; i < 4; ++i)
#pragma unroll
        for (int j = 0; j < 4; ++j) acc[i][j] = (f32x4){0.f, 0.f, 0.f, 0.f};

    stage(0, 0);
    barrier_vm0();
#pragma unroll 2
    for (int it = 0; it < 32; ++it) {
        const int cur = it & 1;
        if (it < 31) stage(cur ^ 1, (it + 1) * 32);
        const char* Ac = As[cur]; const char* Bc = Bs[cur];
        bh8 af[4], bf[4];
#pragma unroll
        for (int mf = 0; mf < 4; ++mf)
            af[mf] = *(const bh8*)(Ac + (wm * 64 + mf * 16 + l) * 64 + quad * 16);
#pragma unroll
        for (int nf = 0; nf < 4; ++nf)
            bf[nf] = *(const bh8*)(Bc + (wn * 64 + nf * 16 + l) * 64 + quad * 16);
#pragma unroll
        for (int mf = 0; mf < 4; ++mf)
#pragma unroll
            for (int nf = 0; nf < 4; ++nf)
                acc[mf][nf] = __builtin_amdgcn_mfma_f32_16x16x32_bf16(af[mf], bf[nf], acc[mf][nf], 0, 0, 0);
        barrier_vm0();
    }

#pragma unroll
    for (int mf = 0; mf < 4; ++mf)
#pragma unroll
        for (int nf = 0; nf < 4; ++nf) {
            const int mb = m0 + wm * 64 + mf * 16 + quad * 4;
            const int n  = n0 + wn * 64 + nf * 16 + l;
#pragma unroll
            for (int reg = 0; reg < 4; ++reg)
                Cout[(size_t)(mb + reg) * OUTn + n] = acc[mf][nf][reg];
        }
}

// ---------------------------------------------------------------------------
// MFMA flash attention v4 = round-4 body + 40KB LDS for 4 blocks/CU.
// S^T formulation, streaming softmax (no running max — scores bounded; exp2
// domain, log2e folded into q). l via ones-MFMA over the same truncated bf16
// P used for PV. Block = (b,h, 128 q), 4 waves x 32 q. 64-key iters, K/V
// double-buffered (glds prefetch + single vm0-barrier per iter). P stashed
// per 32-key half so PS is 2KB/wave (LDS total 40KB -> 4 blocks/CU,
// 4 waves/SIMD for latency hiding).
// ---------------------------------------------------------------------------
__global__ __launch_bounds__(256, 4)
void attn_mfma(const ushort* __restrict__ Qg, const ushort* __restrict__ Kg,
               const ushort* __restrict__ Vtg, ushort* __restrict__ Og)
{
    __shared__ char KT[2][8192];  // (r,d): (d>>5)*4096 + r*64 + (d&31)*2
    __shared__ char VT[2][8192];  // (c,d): d*128 + ((c>>3)^(d&7))*16 + (c&7)*2
    __shared__ char PS[8192];     // per-wave 2KB: (q,k32): q*64 + chunk-XOR(l&3)

    const int tid = threadIdx.x;
    const int w = tid >> 6, lane = tid & 63, quad = lane >> 4, l = lane & 15;
    const int q0 = blockIdx.x * 128;
    const int bh = blockIdx.y, b = bh >> 4, h = bh & 15;
    const ushort* Qp = Qg  + (size_t)bh * Tn * Dn;
    const ushort* Kp = Kg  + (size_t)bh * Tn * Dn;
    const ushort* Vp = Vtg + (size_t)bh * Dn * Tn;   // [d][t]

    auto stageK = [&](char* buf, int kt) {
#pragma unroll
        for (int rr = 0; rr < 2; ++rr) {
            const int rho = w * 2 + rr;                    // 0..7
            const int r  = (rho & 3) * 16 + (lane >> 2);   // key row 0..63
            const int dq = (rho >> 2) * 32 + (lane & 3) * 8;
            glds16(Kp + (size_t)(kt * 64 + r) * Dn + dq, buf + rho * 1024 + lane * 16);
        }
    };
    auto stageV = [&](char* buf, int kt) {
#pragma unroll
        for (int rr = 0; rr < 2; ++rr) {
            const int rho = w * 2 + rr;
            const int d = rho * 8 + (lane >> 3);           // 0..63
            const int csrc = (lane & 7) ^ ((lane >> 3) & 7);
            glds16(Vp + (size_t)d * Tn + kt * 64 + csrc * 8, buf + rho * 1024 + lane * 16);
        }
    };

    // ---- Q frags direct from global (B-operand layout; once per block) ----
    bh8 qf[2][2];
#pragma unroll
    for (int nt = 0; nt < 2; ++nt)
#pragma unroll
        for (int ks = 0; ks < 2; ++ks)
            qf[nt][ks] = *(const bh8*)(Qp + (size_t)(q0 + w * 32 + nt * 16 + l) * Dn + ks * 32 + quad * 8);

    bh8 ones;
#pragma unroll
    for (int i = 0; i < 8; ++i) ones[i] = (short)0x3F80;   // bf16 1.0

    f32x4 oacc[2][4], lacc[2];
#pragma unroll
    for (int nt = 0; nt < 2; ++nt) {
        lacc[nt] = (f32x4){0.f, 0.f, 0.f, 0.f};
#pragma unroll
        for (int dt = 0; dt < 4; ++dt) oacc[nt][dt] = (f32x4){0.f, 0.f, 0.f, 0.f};
    }

    char* Pw = PS + w * 2048;
    const f32x4 zero = (f32x4){0.f, 0.f, 0.f, 0.f};

    stageK(KT[0], 0);
    stageV(VT[0], 0);
    barrier_vm0();

#pragma unroll 2
    for (int kt = 0; kt < Tn / 64; ++kt) {
        const int cur = kt & 1;
        if (kt < Tn / 64 - 1) {           // prefetch next tile (in flight all body)
            stageK(KT[cur ^ 1], kt + 1);
            stageV(VT[cur ^ 1], kt + 1);
        }
        const char* Kc = KT[cur];
        const char* Vc = VT[cur];

        // ---- two 32-key halves: S -> exp -> P-stash -> PV ----
#pragma unroll
        for (int hh = 0; hh < 2; ++hh) {
            // K frags for keys hh*32..+31 (A-operand: m=key, k=d)
            bh8 kf[2][2];
#pragma unroll
            for (int k8l = 0; k8l < 2; ++k8l)
#pragma unroll
                for (int ks = 0; ks < 2; ++ks)
                    kf[k8l][ks] = *(const bh8*)(Kc + ks * 4096 + ((hh * 2 + k8l) * 16 + l) * 64 + quad * 16);

            // S^T = K Q^T : rows=keys(quad*4+reg), col=q(l)
            f32x4 st[2][2];
#pragma unroll
            for (int nt = 0; nt < 2; ++nt)
#pragma unroll
                for (int k8l = 0; k8l < 2; ++k8l) {
                    st[nt][k8l] = __builtin_amdgcn_mfma_f32_16x16x32_bf16(kf[k8l][0], qf[nt][0], zero, 0, 0, 0);
                    st[nt][k8l] = __builtin_amdgcn_mfma_f32_16x16x32_bf16(kf[k8l][1], qf[nt][1], st[nt][k8l], 0, 0, 0);
                }

            // P = exp2(S) -> trunc-bf16 -> wave-private PS
#pragma unroll
            for (int nt = 0; nt < 2; ++nt)
#pragma unroll
                for (int k8l = 0; k8l < 2; ++k8l) {
                    const float e0 = __builtin_amdgcn_exp2f(st[nt][k8l][0]);
                    const float e1 = __builtin_amdgcn_exp2f(st[nt][k8l][1]);
                    const float e2 = __builtin_amdgcn_exp2f(st[nt][k8l][2]);
                    const float e3 = __builtin_amdgcn_exp2f(st[nt][k8l][3]);
                    uint2 p;
                    p.x = pack_trunc(e0, e1);
                    p.y = pack_trunc(e2, e3);
                    const int x = (k8l * 2 + (quad >> 1)) ^ (l & 3);
                    *(uint2*)(Pw + (nt * 16 + l) * 64 + x * 16 + (quad & 1) * 8) = p;
                }
            __builtin_amdgcn_s_waitcnt(0xC07F);  // lgkmcnt(0): PS visible to own wave

            // O += P V ; l += ones*P (B-operand pf: n=q, k=keys of half)
            bh8 pf[2];
#pragma unroll
            for (int nt = 0; nt < 2; ++nt)
                pf[nt] = *(const bh8*)(Pw + (nt * 16 + l) * 64 + ((quad ^ (l & 3)) * 16));
#pragma unroll
            for (int nt = 0; nt < 2; ++nt)
                lacc[nt] = __builtin_amdgcn_mfma_f32_16x16x32_bf16(ones, pf[nt], lacc[nt], 0, 0, 0);
#pragma unroll
            for (int dt = 0; dt < 4; ++dt) {
                bh8 vf = *(const bh8*)(Vc + (dt * 16 + l) * 128 + (((hh * 4 + quad) ^ (l & 7)) * 16));
#pragma unroll
                for (int nt = 0; nt < 2; ++nt)
                    oacc[nt][dt] = __builtin_amdgcn_mfma_f32_16x16x32_bf16(vf, pf[nt], oacc[nt][dt], 0, 0, 0);
            }
        }
        barrier_vm0();   // prefetch drained; all waves done with KT/VT cur
    }

    // ---- epilogue: normalize, write bf16 [B,T,H*D]; O^T: col=q(l), row=d ----
#pragma unroll
    for (int nt = 0; nt < 2; ++nt) {
        const float inv = 1.0f / lacc[nt][0];
        const int t = q0 + w * 32 + nt * 16 + l;
#pragma unroll
        for (int dt = 0; dt < 4; ++dt) {
            uint2 p;
            p.x = pack_rne(oacc[nt][dt][0] * inv, oacc[nt][dt][1] * inv);
            p.y = pack_rne(oacc[nt][dt][2] * inv, oacc[nt][dt][3] * inv);
            *(uint2*)(Og + ((size_t)(b * Tn + t)) * INNERn + h * 64 + dt * 16 + quad * 4) = p;
        }
    }
}

// ---------------------------------------------------------------------------
extern "C" void kernel_launch(void* const* d_in, const int* in_sizes, int n_in,
                              void* d_out, int out_size, void* d_ws, size_t ws_size,
                              hipStream_t stream)
{
    const float* x  = (const float*)d_in[0];
    const float* Wk = (const float*)d_in[1];
    const float* Wq = (const float*)d_in[2];
    const float* Wv = (const float*)d_in[3];
    const float* Wp = (const float*)d_in[4];
    float* out = (float*)d_out;

    // workspace (all bf16): x | Wk | Wq | Wv | Wp | q | k | vT | ao
    ushort* xb  = (ushort*)d_ws;
    ushort* wkb = xb  + (size_t)Mn * Cn;
    ushort* wqb = wkb + (size_t)INNERn * Cn;
    ushort* wvb = wqb + (size_t)INNERn * Cn;
    ushort* wpb = wvb + (size_t)INNERn * Cn;
    ushort* qw  = wpb + (size_t)OUTn * INNERn;
    ushort* kw  = qw  + (size_t)Mn * INNERn;
    ushort* vtw = kw  + (size_t)Mn * INNERn;   // [B,H,D,T]
    ushort* aow = vtw + (size_t)Mn * INNERn;

    const dim3 blk(256);
    cvt_all<<<dim3(8192 + 4096), blk, 0, stream>>>(x, Wk, Wq, Wv, Wp,
                                                   xb, wkb, wqb, wvb, wpb);

    // q folds d^-0.5 * log2(e) so softmax runs in exp2 domain
    gemm_qkv<<<dim3(3 * 8, Mn / 128), blk, 0, stream>>>(xb, wqb, wkb, wvb,
                                                        qw, kw, vtw, 0.125f * 1.44269504f);

    attn_mfma<<<dim3(Tn / 128, Bn * Hn), blk, 0, stream>>>(qw, kw, vtw, aow);

    gemm_po<<<dim3(OUTn / 128, Mn / 128), blk, 0, stream>>>(aow, wpb, out);
}